// Round 5
// baseline (474.426 us; speedup 1.0000x reference)
//
#include <hip/hip_runtime.h>
#include <math.h>

#define N 4096
#define DD 256
#define CAP 512      // per-column candidate capacity (~224 expected with 128-row slabs)
#define RCAP 256     // per-row support capacity (beta gather only)
#define LEAKY 0.2f

// INSTRUMENTATION ROUND: pure kernels repeat their body REPS_* times so they
// exceed the 121us poison fills and surface in rocprof's top-5 with counters.
// Writes are idempotent -> results identical; total-time delta decomposes cost.
#define REPS_COLTAU 8
#define REPS_ROW    4

typedef float v4f __attribute__((ext_vector_type(4)));

// nontemporal 16B store of a HIP float4 through a native clang vector type
__device__ __forceinline__ void nt_store4(const float4& p, float4* dst){
  v4f v = { p.x, p.y, p.z, p.w };
  __builtin_nontemporal_store(v, (v4f*)dst);
}

// ---------------------------------------------------------------------------
// Pass 1 (COALESCED): column candidate compaction. (unchanged from round 3)
// ---------------------------------------------------------------------------
__global__ __launch_bounds__(256) void k_colcand3(const float* __restrict__ cost,
      int* __restrict__ cnt, float* __restrict__ candv, int* __restrict__ candi){
  const int tc = threadIdx.x & 63;        // column within group (64)
  const int tr = threadIdx.x >> 6;        // row chunk (4 chunks of 32)
  const int j  = blockIdx.x * 64 + tc;
  const int r0 = blockIdx.y * 128 + tr * 32;
  const float* p = cost + (size_t)r0 * N + j;

  float v[32];
  #pragma unroll
  for (int r = 0; r < 32; ++r) v[r] = -p[(size_t)r * N];

  float m = v[0];
  #pragma unroll
  for (int r = 1; r < 32; ++r) m = fmaxf(m, v[r]);

  __shared__ float smax[4][64];
  __shared__ int   scnt[4][64];
  __shared__ int   sbase[64];
  smax[tr][tc] = m;
  __syncthreads();
  const float m4 = fmaxf(fmaxf(smax[0][tc], smax[1][tc]),
                         fmaxf(smax[2][tc], smax[3][tc]));
  const float th = m4 - 1.0f;

  int nc = 0;
  #pragma unroll
  for (int r = 0; r < 32; ++r) nc += (v[r] > th) ? 1 : 0;
  scnt[tr][tc] = nc;
  __syncthreads();

  int myoff = 0;
  #pragma unroll
  for (int s = 0; s < 4; ++s) if (s < tr) myoff += scnt[s][tc];
  const int tot = scnt[0][tc] + scnt[1][tc] + scnt[2][tc] + scnt[3][tc];

  if (tr == 0) sbase[tc] = atomicAdd(&cnt[j], tot);
  __syncthreads();

  int q = sbase[tc] + myoff;
  #pragma unroll
  for (int r = 0; r < 32; ++r){
    if (v[r] > th){
      if (q < CAP){
        candv[(size_t)j * CAP + q] = v[r];
        candi[(size_t)j * CAP + q] = r0 + r;
      }
      ++q;
    }
  }
}

// ---------------------------------------------------------------------------
// Column tau (Michelot) + alpha. PURE -> internally repeated REPS_COLTAU x.
// ---------------------------------------------------------------------------
__global__ __launch_bounds__(256) void k_coltau(const int* __restrict__ cnt,
      const float* __restrict__ candv, const int* __restrict__ candi,
      const float* __restrict__ rowvecs, float* __restrict__ tau_out,
      float* __restrict__ alpha){
  const int t = threadIdx.x, w = t >> 6, lane = t & 63;
  const int j = blockIdx.x * 4 + w;
  __shared__ float sup_v[4][CAP];
  __shared__ int   sup_i[4][CAP];

  for (int rep = 0; rep < REPS_COLTAU; ++rep){
    const int c = min(cnt[j], CAP);
    const float* cv = candv + (size_t)j * CAP;
    const int*   ci = candi + (size_t)j * CAP;

    float v[8]; int id[8];
    #pragma unroll
    for (int s = 0; s < 8; ++s){
      int l = s * 64 + lane;
      v[s]  = (l < c) ? cv[l] : -3.4e38f;
      id[s] = (l < c) ? ci[l] : 0;
    }

    float tau = -3.0e38f;
    for (int it = 0; it < 40; ++it){
      float sum = 0.0f, cf = 0.0f;
      #pragma unroll
      for (int s = 0; s < 8; ++s) if (v[s] > tau){ sum += v[s]; cf += 1.0f; }
      for (int off = 32; off; off >>= 1){ sum += __shfl_xor(sum, off); cf += __shfl_xor(cf, off); }
      float nt = (sum - 1.0f) / cf;
      if (nt == tau) break;
      tau = nt;
    }
    if (lane == 0) tau_out[j] = tau;

    int base = 0;
    #pragma unroll
    for (int s = 0; s < 8; ++s){
      bool pred = (v[s] > tau);
      unsigned long long mk = __ballot(pred);
      if (pred){
        int pos = base + __popcll(mk & ((1ULL << lane) - 1ULL));
        sup_v[w][pos] = v[s] - tau;
        sup_i[w][pos] = id[s];
      }
      base += __popcll(mk);
    }
    const int ns = base;
    __builtin_amdgcn_wave_barrier();
    __asm__ volatile("s_waitcnt lgkmcnt(0)");

    float a0 = 0, a1 = 0, a2 = 0, a3 = 0;
    #pragma unroll 4
    for (int l = 0; l < ns; ++l){
      float pp = sup_v[w][l];
      const float* ar = rowvecs + (size_t)sup_i[w][l] * DD;
      a0 += pp * ar[lane];        a1 += pp * ar[64 + lane];
      a2 += pp * ar[128 + lane];  a3 += pp * ar[192 + lane];
    }
    float* al = alpha + (size_t)j * DD;
    al[lane] = a0; al[64 + lane] = a1; al[128 + lane] = a2; al[192 + lane] = a3;

    __asm__ volatile("" ::: "memory");   // defeat LICM/DSE across reps
  }
}

// ---------------------------------------------------------------------------
// Row sparsemax per-wave + outputs + beta. PURE -> repeated REPS_ROW x.
// ---------------------------------------------------------------------------
__global__ __launch_bounds__(256) void k_row(const float* __restrict__ cost,
      const float* __restrict__ colvecs, const float* __restrict__ tau_col,
      float* __restrict__ out_row, float* __restrict__ out_col,
      float* __restrict__ beta){
  const int t = threadIdx.x, w = t >> 6, lane = t & 63;
  const int i = blockIdx.x * 4 + w;
  __shared__ float sup_v[4][RCAP];
  __shared__ int   sup_j[4][RCAP];

  for (int rep = 0; rep < REPS_ROW; ++rep){
    const float4* row4 = (const float4*)(cost + (size_t)i * N);
    float4 x4[16];
    #pragma unroll
    for (int s = 0; s < 16; ++s){
      float4 v = row4[lane + s * 64];
      x4[s] = make_float4(-v.x, -v.y, -v.z, -v.w);
    }

    float m = -3.4e38f;
    #pragma unroll
    for (int s = 0; s < 16; ++s)
      m = fmaxf(m, fmaxf(fmaxf(x4[s].x, x4[s].y), fmaxf(x4[s].z, x4[s].w)));
    #pragma unroll
    for (int off = 32; off; off >>= 1) m = fmaxf(m, __shfl_xor(m, off));

    float tau = m - 1.0f;
    for (int it = 0; it < 40; ++it){
      float sum = 0.0f, cf = 0.0f;
      #pragma unroll
      for (int s = 0; s < 16; ++s){
        const float* e = &x4[s].x;
        #pragma unroll
        for (int c = 0; c < 4; ++c)
          if (e[c] > tau){ sum += e[c]; cf += 1.0f; }
      }
      for (int off = 32; off; off >>= 1){ sum += __shfl_xor(sum, off); cf += __shfl_xor(cf, off); }
      float nt = (sum - 1.0f) / cf;
      if (nt == tau) break;
      tau = nt;
    }

    const float4* tau4 = (const float4*)tau_col;
    float4* orow4 = (float4*)(out_row + (size_t)i * N);
    float4* ocol4 = (float4*)(out_col + (size_t)i * N);
    int base = 0;
    #pragma unroll
    for (int s = 0; s < 16; ++s){
      float4 p;
      p.x = fmaxf(x4[s].x - tau, 0.0f);
      p.y = fmaxf(x4[s].y - tau, 0.0f);
      p.z = fmaxf(x4[s].z - tau, 0.0f);
      p.w = fmaxf(x4[s].w - tau, 0.0f);
      nt_store4(p, &orow4[lane + s * 64]);

      float4 tt = tau4[lane + s * 64];
      float4 pc;
      pc.x = fmaxf(x4[s].x - tt.x, 0.0f);
      pc.y = fmaxf(x4[s].y - tt.y, 0.0f);
      pc.z = fmaxf(x4[s].z - tt.z, 0.0f);
      pc.w = fmaxf(x4[s].w - tt.w, 0.0f);
      nt_store4(pc, &ocol4[lane + s * 64]);

      int jb = 4 * (lane + s * 64);
      const float* e = &p.x;
      #pragma unroll
      for (int c = 0; c < 4; ++c){
        bool pred = (e[c] > 0.0f);
        unsigned long long mk = __ballot(pred);
        if (pred){
          int pos = base + __popcll(mk & ((1ULL << lane) - 1ULL));
          if (pos < RCAP){ sup_v[w][pos] = e[c]; sup_j[w][pos] = jb + c; }
        }
        base += __popcll(mk);
      }
    }
    const int ns = min(base, RCAP);
    __builtin_amdgcn_wave_barrier();
    __asm__ volatile("s_waitcnt lgkmcnt(0)");

    float a0 = 0, a1 = 0, a2 = 0, a3 = 0;
    #pragma unroll 4
    for (int l = 0; l < ns; ++l){
      float pp = sup_v[w][l];
      const float* cr = colvecs + (size_t)sup_j[w][l] * DD;
      a0 += pp * cr[lane];        a1 += pp * cr[64 + lane];
      a2 += pp * cr[128 + lane];  a3 += pp * cr[192 + lane];
    }
    float* be = beta + (size_t)i * DD;
    be[lane] = a0; be[64 + lane] = a1; be[128 + lane] = a2; be[192 + lane] = a3;

    __asm__ volatile("" ::: "memory");   // defeat LICM/DSE across reps
  }
}

// ---------------------------------------------------------------------------
// G(x) = leaky_relu(x @ W + b); accumulate column sums for the means
// ---------------------------------------------------------------------------
__global__ __launch_bounds__(256) void k_G(const float* __restrict__ beta,
      const float* __restrict__ alpha, const float* __restrict__ W,
      const float* __restrict__ bG, float* __restrict__ vsum){
  int t = threadIdx.x, side = blockIdx.y, r0 = blockIdx.x * 16;
  const float* src = side ? alpha : beta;
  __shared__ float sB[16 * 256];
  #pragma unroll
  for (int k = 0; k < 16; ++k) sB[k * 256 + t] = src[(size_t)(r0 + k) * 256 + t];
  __syncthreads();
  float acc[16];
  float bg = bG[t];
  #pragma unroll
  for (int r = 0; r < 16; ++r) acc[r] = bg;
  const float4* sB4 = (const float4*)sB;
  for (int d4 = 0; d4 < 64; ++d4){
    int d = d4 * 4;
    float w0 = W[(size_t)d * 256 + t];
    float w1 = W[(size_t)(d + 1) * 256 + t];
    float w2 = W[(size_t)(d + 2) * 256 + t];
    float w3 = W[(size_t)(d + 3) * 256 + t];
    #pragma unroll
    for (int r = 0; r < 16; ++r){
      float4 s = sB4[r * 64 + d4];
      acc[r] += s.x * w0 + s.y * w1 + s.z * w2 + s.w * w3;
    }
  }
  float s = 0.0f;
  #pragma unroll
  for (int r = 0; r < 16; ++r){ float u = acc[r]; s += (u > 0.0f) ? u : LEAKY * u; }
  atomicAdd(&vsum[side * 256 + t], s);
}

// cosine cost scalar
__global__ __launch_bounds__(256) void k_final(const float* __restrict__ vsum,
                                               float* __restrict__ y){
  int t = threadIdx.x, w = t >> 6, lane = t & 63;
  __shared__ float rd[3][4];
  float v1 = vsum[t]       * (1.0f / 4096.0f);
  float v2 = vsum[256 + t] * (1.0f / 4096.0f);
  float d = v1 * v2, a = v1 * v1, b = v2 * v2;
  for (int off = 32; off; off >>= 1){
    d += __shfl_xor(d, off); a += __shfl_xor(a, off); b += __shfl_xor(b, off);
  }
  if (lane == 0){ rd[0][w] = d; rd[1][w] = a; rd[2][w] = b; }
  __syncthreads();
  if (t == 0){
    float dd = rd[0][0] + rd[0][1] + rd[0][2] + rd[0][3];
    float aa = rd[1][0] + rd[1][1] + rd[1][2] + rd[1][3];
    float bb = rd[2][0] + rd[2][1] + rd[2][2] + rd[2][3];
    y[0] = 1.0f - dd / (sqrtf(aa) * sqrtf(bb) + 1e-8f);
  }
}

// write-only broadcast of y into out0 (nontemporal pure write stream),
// grid-stride: 2048 blocks x 8 float4/thread -> covers all 16.7M floats
__global__ __launch_bounds__(256) void k_fill(const float* __restrict__ ypt,
                                              float4* __restrict__ out0){
  const float y = ypt[0];
  const float4 f = make_float4(y, y, y, y);
  int idx = blockIdx.x * 256 + threadIdx.x;
  #pragma unroll
  for (int k = 0; k < 8; ++k)
    nt_store4(f, &out0[idx + k * 524288]);
}

extern "C" void kernel_launch(void* const* d_in, const int* in_sizes, int n_in,
                              void* d_out, int out_size, void* d_ws, size_t ws_size,
                              hipStream_t stream){
  const float* rowv = (const float*)d_in[0];   // [4096,256]
  const float* colv = (const float*)d_in[1];   // [4096,256]
  const float* cost = (const float*)d_in[2];   // [4096,4096]
  const float* W    = (const float*)d_in[3];   // [256,256]
  const float* bG   = (const float*)d_in[4];   // [256]

  float* out0    = (float*)d_out;
  float* out_row = out0 + (size_t)N * N;
  float* out_col = out0 + 2 * (size_t)N * N;

  int*   cnt   = (int*)d_ws;
  float* vsum  = (float*)d_ws + 4096;
  float* tau   = (float*)d_ws + 4608;
  float* beta  = (float*)d_ws + 8704;
  float* alpha = (float*)d_ws + 8704 + 1048576;
  float* candv = (float*)d_ws + 8704 + 2 * 1048576;
  int*   candi = (int*)d_ws   + 8704 + 4 * 1048576;
  float* ypt   = (float*)d_ws + 8704 + 6 * 1048576;

  hipMemsetAsync(d_ws, 0, (size_t)4608 * 4, stream);

  hipLaunchKernelGGL(k_colcand3, dim3(64, 32), dim3(256), 0, stream, cost, cnt, candv, candi);
  hipLaunchKernelGGL(k_coltau,   dim3(1024),   dim3(256), 0, stream, cnt, candv, candi, rowv, tau, alpha);
  hipLaunchKernelGGL(k_row,      dim3(1024),   dim3(256), 0, stream, cost, colv, tau, out_row, out_col, beta);
  hipLaunchKernelGGL(k_G,        dim3(256,2),  dim3(256), 0, stream, beta, alpha, W, bG, vsum);
  hipLaunchKernelGGL(k_final,    dim3(1),      dim3(256), 0, stream, vsum, ypt);
  hipLaunchKernelGGL(k_fill,     dim3(2048),   dim3(256), 0, stream, ypt, (float4*)out0);
}

// Round 7
// 339.003 us; speedup vs baseline: 1.3995x; 1.3995x over previous
//
#include <hip/hip_runtime.h>
#include <math.h>

#define N 4096
#define DD 256
#define CAP 512      // per-column candidate capacity (~224 expected, 128-row slabs)
#define RCAP 256     // per-row candidate capacity (tau + beta gather)
#define SCAP 48      // per-(column,unit) LDS staging slots (overflow -> direct)
#define LEAKY 0.2f

typedef float v4f __attribute__((ext_vector_type(4)));

// nontemporal 16B store of a HIP float4 through a native clang vector type
__device__ __forceinline__ void nt_store4(const float4& p, float4* dst){
  v4f v = { p.x, p.y, p.z, p.w };
  __builtin_nontemporal_store(v, (v4f*)dst);
}

// ---------------------------------------------------------------------------
// Pass 1: column candidate compaction, COALESCED STORES.
// Block = 256 thr = 64 cols x 4 row-chunks of 32 -> 128-row slab. Wave = 64
// consecutive columns of one row -> 256 B contiguous loads.
// th = m_slab - 1 <= M_j - 1 <= tau*_j  ==> candidate set is a provable
// superset of the column support (Michelot on a superset is exact).
// Candidates staged in LDS (48 slots per column-unit; overflow -> direct
// scattered store, statistically rare), then written as interleaved
// (val, idx) float2 pairs by 4 threads/column -> 32 B contiguous chunks
// instead of ~1.8M scattered 4 B stores. ONE global atomic per (col, unit).
// ---------------------------------------------------------------------------
__global__ __launch_bounds__(256) void k_cand(const float* __restrict__ cost,
      int* __restrict__ cnt, float2* __restrict__ candp){
  const int tc = threadIdx.x & 63;        // column within group (64)
  const int tr = threadIdx.x >> 6;        // row chunk (4 chunks of 32)
  const int j  = blockIdx.x * 64 + tc;
  const int r0 = blockIdx.y * 128;        // slab base row
  const float* p = cost + (size_t)(r0 + tr * 32) * N + j;

  float v[32];
  #pragma unroll
  for (int r = 0; r < 32; ++r) v[r] = -p[(size_t)r * N];

  float m = v[0];
  #pragma unroll
  for (int r = 1; r < 32; ++r) m = fmaxf(m, v[r]);

  __shared__ float smax[4][64];
  __shared__ int   scnt[4][64];
  __shared__ int   sbase[64];
  __shared__ float sval[64][SCAP];
  __shared__ unsigned char sidx[64][SCAP];

  smax[tr][tc] = m;
  __syncthreads();
  const float m4 = fmaxf(fmaxf(smax[0][tc], smax[1][tc]),
                         fmaxf(smax[2][tc], smax[3][tc]));
  const float th = m4 - 1.0f;

  int nc = 0;
  #pragma unroll
  for (int r = 0; r < 32; ++r) nc += (v[r] > th) ? 1 : 0;
  scnt[tr][tc] = nc;
  __syncthreads();

  int myoff = 0;
  #pragma unroll
  for (int s = 0; s < 4; ++s) if (s < tr) myoff += scnt[s][tc];
  const int tot = scnt[0][tc] + scnt[1][tc] + scnt[2][tc] + scnt[3][tc];

  if (tr == 0) sbase[tc] = atomicAdd(&cnt[j], tot);   // 1 atomic/(col,unit)
  __syncthreads();
  const int b = sbase[tc];

  // stage into LDS; overflow (pos >= SCAP) goes direct (rare)
  int pos = myoff;
  #pragma unroll
  for (int r = 0; r < 32; ++r){
    if (v[r] > th){
      if (pos < SCAP){
        sval[tc][pos] = v[r];
        sidx[tc][pos] = (unsigned char)(tr * 32 + r);
      } else {
        int q = b + pos;
        if (q < CAP)
          candp[(size_t)j * CAP + q] =
              make_float2(v[r], __int_as_float(r0 + tr * 32 + r));
      }
      ++pos;
    }
  }
  __syncthreads();

  // coalesced write phase: 4 threads per column, 8 B pairs -> 32 B chunks
  const int lc = threadIdx.x >> 2;        // local column 0..63
  const int qq = threadIdx.x & 3;
  const int jj = blockIdx.x * 64 + lc;
  const int cc = min(scnt[0][lc] + scnt[1][lc] + scnt[2][lc] + scnt[3][lc], SCAP);
  const int bb = sbase[lc];
  for (int s = qq; s < cc; s += 4){
    int q = bb + s;
    if (q < CAP)
      candp[(size_t)jj * CAP + q] =
          make_float2(sval[lc][s], __int_as_float(r0 + (int)sidx[lc][s]));
  }
}

// ---------------------------------------------------------------------------
// Column tau (Michelot on candidates, one wave per column) + alpha[j,:].
// Candidates read as coalesced float2 (val, idx) pairs.
// ---------------------------------------------------------------------------
__global__ __launch_bounds__(256) void k_coltau(const int* __restrict__ cnt,
      const float2* __restrict__ candp,
      const float* __restrict__ rowvecs, float* __restrict__ tau_out,
      float* __restrict__ alpha){
  const int t = threadIdx.x, w = t >> 6, lane = t & 63;
  const int j = blockIdx.x * 4 + w;
  const int c = min(cnt[j], CAP);
  const float2* cp = candp + (size_t)j * CAP;

  float v[8]; int id[8];
  #pragma unroll
  for (int s = 0; s < 8; ++s){
    int l = s * 64 + lane;
    float2 pr = (l < c) ? cp[l] : make_float2(-3.4e38f, 0.0f);
    v[s]  = pr.x;
    id[s] = __float_as_int(pr.y);
  }

  float tau = -3.0e38f;
  for (int it = 0; it < 40; ++it){
    float sum = 0.0f, cf = 0.0f;
    #pragma unroll
    for (int s = 0; s < 8; ++s) if (v[s] > tau){ sum += v[s]; cf += 1.0f; }
    for (int off = 32; off; off >>= 1){ sum += __shfl_xor(sum, off); cf += __shfl_xor(cf, off); }
    float nt = (sum - 1.0f) / cf;
    if (nt == tau) break;
    tau = nt;
  }
  if (lane == 0) tau_out[j] = tau;

  // compact support (v - tau > 0) into per-wave LDS
  __shared__ float sup_v[4][CAP];
  __shared__ int   sup_i[4][CAP];
  int base = 0;
  #pragma unroll
  for (int s = 0; s < 8; ++s){
    bool pred = (v[s] > tau);
    unsigned long long mk = __ballot(pred);
    if (pred){
      int pos = base + __popcll(mk & ((1ULL << lane) - 1ULL));
      sup_v[w][pos] = v[s] - tau;
      sup_i[w][pos] = id[s];
    }
    base += __popcll(mk);
  }
  const int ns = base;
  __builtin_amdgcn_wave_barrier();
  __asm__ volatile("s_waitcnt lgkmcnt(0)");

  float a0 = 0, a1 = 0, a2 = 0, a3 = 0;
  #pragma unroll 4
  for (int l = 0; l < ns; ++l){
    float pp = sup_v[w][l];
    const float* ar = rowvecs + (size_t)sup_i[w][l] * DD;
    a0 += pp * ar[lane];        a1 += pp * ar[64 + lane];
    a2 += pp * ar[128 + lane];  a3 += pp * ar[192 + lane];
  }
  float* al = alpha + (size_t)j * DD;
  al[lane] = a0; al[64 + lane] = a1; al[128 + lane] = a2; al[192 + lane] = a3;
}

// ---------------------------------------------------------------------------
// Row sparsemax, per-wave, CANDIDATE-COMPACTED Michelot:
//  - wave max -> compact {v > M-1} (~20-150 per row) into LDS ONCE
//  - Michelot on 4 compacted regs (not 64 full-row regs x 8 iters)
//  - write out_row/out_col (nontemporal streams)
//  - beta gather filters v - tau > 0 from the same candidate list
// ---------------------------------------------------------------------------
__global__ __launch_bounds__(256) void k_row(const float* __restrict__ cost,
      const float* __restrict__ colvecs, const float* __restrict__ tau_col,
      float* __restrict__ out_row, float* __restrict__ out_col,
      float* __restrict__ beta){
  const int t = threadIdx.x, w = t >> 6, lane = t & 63;
  const int i = blockIdx.x * 4 + w;
  __shared__ float sup_v[4][RCAP];
  __shared__ int   sup_j[4][RCAP];

  const float4* row4 = (const float4*)(cost + (size_t)i * N);
  float4 x4[16];
  #pragma unroll
  for (int s = 0; s < 16; ++s){
    float4 v = row4[lane + s * 64];
    x4[s] = make_float4(-v.x, -v.y, -v.z, -v.w);
  }

  float m = -3.4e38f;
  #pragma unroll
  for (int s = 0; s < 16; ++s)
    m = fmaxf(m, fmaxf(fmaxf(x4[s].x, x4[s].y), fmaxf(x4[s].z, x4[s].w)));
  #pragma unroll
  for (int off = 32; off; off >>= 1) m = fmaxf(m, __shfl_xor(m, off));
  const float th = m - 1.0f;

  // single ballot-compaction of candidates {v > M-1} (superset of support)
  int base = 0;
  #pragma unroll
  for (int s = 0; s < 16; ++s){
    const float* e = &x4[s].x;
    int jb = 4 * (lane + s * 64);
    #pragma unroll
    for (int c = 0; c < 4; ++c){
      bool pred = (e[c] > th);
      unsigned long long mk = __ballot(pred);
      if (pred){
        int pos = base + __popcll(mk & ((1ULL << lane) - 1ULL));
        if (pos < RCAP){ sup_v[w][pos] = e[c]; sup_j[w][pos] = jb + c; }
      }
      base += __popcll(mk);
    }
  }
  const int ns = min(base, RCAP);
  __builtin_amdgcn_wave_barrier();
  __asm__ volatile("s_waitcnt lgkmcnt(0)");

  // Michelot on the compacted set (4 regs/lane), tau0 = M-1 -> exact
  float cv[4];
  #pragma unroll
  for (int s = 0; s < 4; ++s){
    int l = s * 64 + lane;
    cv[s] = (l < ns) ? sup_v[w][l] : -3.4e38f;
  }
  float tau = th;
  for (int it = 0; it < 40; ++it){
    float sum = 0.0f, cf = 0.0f;
    #pragma unroll
    for (int s = 0; s < 4; ++s) if (cv[s] > tau){ sum += cv[s]; cf += 1.0f; }
    for (int off = 32; off; off >>= 1){ sum += __shfl_xor(sum, off); cf += __shfl_xor(cf, off); }
    float nt = (sum - 1.0f) / cf;
    if (nt == tau) break;
    tau = nt;
  }

  // streamed output writes (no ballots in this loop anymore)
  const float4* tau4 = (const float4*)tau_col;   // 16 KB, L2-resident
  float4* orow4 = (float4*)(out_row + (size_t)i * N);
  float4* ocol4 = (float4*)(out_col + (size_t)i * N);
  #pragma unroll
  for (int s = 0; s < 16; ++s){
    float4 p;
    p.x = fmaxf(x4[s].x - tau, 0.0f);
    p.y = fmaxf(x4[s].y - tau, 0.0f);
    p.z = fmaxf(x4[s].z - tau, 0.0f);
    p.w = fmaxf(x4[s].w - tau, 0.0f);
    nt_store4(p, &orow4[lane + s * 64]);

    float4 tt = tau4[lane + s * 64];
    float4 pc;
    pc.x = fmaxf(x4[s].x - tt.x, 0.0f);
    pc.y = fmaxf(x4[s].y - tt.y, 0.0f);
    pc.z = fmaxf(x4[s].z - tt.z, 0.0f);
    pc.w = fmaxf(x4[s].w - tt.w, 0.0f);
    nt_store4(pc, &ocol4[lane + s * 64]);
  }

  // beta gather over candidates, filtered to the true support (v - tau > 0)
  float a0 = 0, a1 = 0, a2 = 0, a3 = 0;
  for (int l = 0; l < ns; ++l){
    float pp = sup_v[w][l] - tau;
    if (pp > 0.0f){
      const float* cr = colvecs + (size_t)sup_j[w][l] * DD;
      a0 += pp * cr[lane];        a1 += pp * cr[64 + lane];
      a2 += pp * cr[128 + lane];  a3 += pp * cr[192 + lane];
    }
  }
  float* be = beta + (size_t)i * DD;
  be[lane] = a0; be[64 + lane] = a1; be[128 + lane] = a2; be[192 + lane] = a3;
}

// ---------------------------------------------------------------------------
// G(x) = leaky_relu(x @ W + b); accumulate column sums for the means
// ---------------------------------------------------------------------------
__global__ __launch_bounds__(256) void k_G(const float* __restrict__ beta,
      const float* __restrict__ alpha, const float* __restrict__ W,
      const float* __restrict__ bG, float* __restrict__ vsum){
  int t = threadIdx.x, side = blockIdx.y, r0 = blockIdx.x * 16;
  const float* src = side ? alpha : beta;
  __shared__ float sB[16 * 256];
  #pragma unroll
  for (int k = 0; k < 16; ++k) sB[k * 256 + t] = src[(size_t)(r0 + k) * 256 + t];
  __syncthreads();
  float acc[16];
  float bg = bG[t];
  #pragma unroll
  for (int r = 0; r < 16; ++r) acc[r] = bg;
  const float4* sB4 = (const float4*)sB;
  for (int d4 = 0; d4 < 64; ++d4){
    int d = d4 * 4;
    float w0 = W[(size_t)d * 256 + t];
    float w1 = W[(size_t)(d + 1) * 256 + t];
    float w2 = W[(size_t)(d + 2) * 256 + t];
    float w3 = W[(size_t)(d + 3) * 256 + t];
    #pragma unroll
    for (int r = 0; r < 16; ++r){
      float4 s = sB4[r * 64 + d4];
      acc[r] += s.x * w0 + s.y * w1 + s.z * w2 + s.w * w3;
    }
  }
  float s = 0.0f;
  #pragma unroll
  for (int r = 0; r < 16; ++r){ float u = acc[r]; s += (u > 0.0f) ? u : LEAKY * u; }
  atomicAdd(&vsum[side * 256 + t], s);
}

// cosine cost scalar
__global__ __launch_bounds__(256) void k_final(const float* __restrict__ vsum,
                                               float* __restrict__ y){
  int t = threadIdx.x, w = t >> 6, lane = t & 63;
  __shared__ float rd[3][4];
  float v1 = vsum[t]       * (1.0f / 4096.0f);
  float v2 = vsum[256 + t] * (1.0f / 4096.0f);
  float d = v1 * v2, a = v1 * v1, b = v2 * v2;
  for (int off = 32; off; off >>= 1){
    d += __shfl_xor(d, off); a += __shfl_xor(a, off); b += __shfl_xor(b, off);
  }
  if (lane == 0){ rd[0][w] = d; rd[1][w] = a; rd[2][w] = b; }
  __syncthreads();
  if (t == 0){
    float dd = rd[0][0] + rd[0][1] + rd[0][2] + rd[0][3];
    float aa = rd[1][0] + rd[1][1] + rd[1][2] + rd[1][3];
    float bb = rd[2][0] + rd[2][1] + rd[2][2] + rd[2][3];
    y[0] = 1.0f - dd / (sqrtf(aa) * sqrtf(bb) + 1e-8f);
  }
}

// write-only broadcast of y into out0 (nontemporal pure write stream)
__global__ __launch_bounds__(256) void k_fill(const float* __restrict__ ypt,
                                              float4* __restrict__ out0){
  const float y = ypt[0];
  const float4 f = make_float4(y, y, y, y);
  int idx = blockIdx.x * 256 + threadIdx.x;
  #pragma unroll
  for (int k = 0; k < 8; ++k)
    nt_store4(f, &out0[idx + k * 524288]);
}

extern "C" void kernel_launch(void* const* d_in, const int* in_sizes, int n_in,
                              void* d_out, int out_size, void* d_ws, size_t ws_size,
                              hipStream_t stream){
  const float* rowv = (const float*)d_in[0];   // [4096,256]
  const float* colv = (const float*)d_in[1];   // [4096,256]
  const float* cost = (const float*)d_in[2];   // [4096,4096]
  const float* W    = (const float*)d_in[3];   // [256,256]
  const float* bG   = (const float*)d_in[4];   // [256]

  float* out0    = (float*)d_out;
  float* out_row = out0 + (size_t)N * N;
  float* out_col = out0 + 2 * (size_t)N * N;

  int*    cnt   = (int*)d_ws;
  float*  vsum  = (float*)d_ws + 4096;
  float*  tau   = (float*)d_ws + 4608;
  float*  beta  = (float*)d_ws + 8704;
  float*  alpha = (float*)d_ws + 8704 + 1048576;
  float2* candp = (float2*)((float*)d_ws + 8704 + 2 * 1048576);  // 16.8 MB pairs
  float*  ypt   = (float*)d_ws + 8704 + 6 * 1048576;

  hipMemsetAsync(d_ws, 0, (size_t)4608 * 4, stream);   // cnt + vsum

  hipLaunchKernelGGL(k_cand,   dim3(64, 32), dim3(256), 0, stream, cost, cnt, candp);
  hipLaunchKernelGGL(k_coltau, dim3(1024),   dim3(256), 0, stream, cnt, candp, rowv, tau, alpha);
  hipLaunchKernelGGL(k_row,    dim3(1024),   dim3(256), 0, stream, cost, colv, tau, out_row, out_col, beta);
  hipLaunchKernelGGL(k_G,      dim3(256,2),  dim3(256), 0, stream, beta, alpha, W, bG, vsum);
  hipLaunchKernelGGL(k_final,  dim3(1),      dim3(256), 0, stream, vsum, ypt);
  hipLaunchKernelGGL(k_fill,   dim3(2048),   dim3(256), 0, stream, ypt, (float4*)out0);
}